// Round 10
// baseline (191.945 us; speedup 1.0000x reference)
//
#include <hip/hip_runtime.h>
#include <math.h>

typedef float f2 __attribute__((ext_vector_type(2)));
typedef float f2u __attribute__((ext_vector_type(2), aligned(4)));
typedef float f4 __attribute__((ext_vector_type(4)));

#define BN 8
#define CIN 3
#define HH 512
#define WW 512
#define KK 9
#define PATCH 27

// ws layout (floats):
//  A [0,756): conv weights: elem i (0..26), 28 floats each: r=2q+half ->
//             q<13: w_off[(2q+half)*27+i]; q==13: half? 0 : w_off[26*27+i]
//  B [756,900): per-tap k, 16 floats: r<12: c=r>>2,o=r&3 -> o<3 ? w_def[o*27+c*9+k] : 0;
//             r==12: b_off[2k]; r==13: b_off[2k+1]; r==14: b_off[18+k]; r==15: 0
//  C [900,928): ow-init pairs: r=2q+half -> q<13: b_off[2q+half]; q==13: half? 0 : b_off[26]
__global__ void reorder_weights(const float* __restrict__ w_off,
                                const float* __restrict__ b_off,
                                const float* __restrict__ w_def,
                                float* __restrict__ ws)
{
    for (int idx = threadIdx.x; idx < 928; idx += blockDim.x) {
        float v = 0.0f;
        if (idx < 756) {
            const int i = idx / 28, r = idx % 28;
            const int q = r >> 1, half = r & 1;
            if (q < 13)      v = w_off[(2 * q + half) * PATCH + i];
            else if (!half)  v = w_off[26 * PATCH + i];
        } else if (idx < 900) {
            const int t = idx - 756;
            const int k = t / 16, r = t % 16;
            if (r < 12) {
                const int c = r >> 2, o = r & 3;
                if (o < 3) v = w_def[o * PATCH + c * KK + k];
            } else if (r == 12) v = b_off[2 * k];
            else if (r == 13)   v = b_off[2 * k + 1];
            else if (r == 14)   v = b_off[18 + k];
        } else {
            const int r = idx - 900;
            const int q = r >> 1, half = r & 1;
            if (q < 13)      v = b_off[2 * q + half];
            else if (!half)  v = b_off[26];
        }
        ws[idx] = v;
    }
}

__global__ __launch_bounds__(256) void deform_fused_kernel(
    const float* __restrict__ x,
    const float* __restrict__ wsw,    // reordered weights, 928 floats (uniform -> SMEM)
    const float* __restrict__ b_def,
    float* __restrict__ out)
{
    const int w = blockIdx.x * blockDim.x + threadIdx.x;
    const int h = blockIdx.y;
    const int b = blockIdx.z;

    const size_t plane = (size_t)HH * WW;
    const float* xb = x + (size_t)b * CIN * plane;

    // ---- 3x3x3 zero-padded patch, flat index = c*9 + t ----
    float patch[PATCH];
    #pragma unroll
    for (int c = 0; c < CIN; ++c) {
        const float* xp = xb + c * plane;
        #pragma unroll
        for (int t = 0; t < KK; ++t) {
            const int yy = h + t / 3 - 1;
            const int xx = w + t % 3 - 1;
            const bool in = ((unsigned)yy < HH) & ((unsigned)xx < WW);
            const int yc = min(max(yy, 0), HH - 1);
            const int xc = min(max(xx, 0), WW - 1);
            patch[c * KK + t] = in ? xp[yc * WW + xc] : 0.0f;
        }
    }

    // ---- hoisted offset conv: 27 channels as 14 packed pairs (pair13.y dummy) ----
    f2 ow[14];
    #pragma unroll
    for (int q = 0; q < 14; ++q) ow[q] = *(const f2*)(wsw + 900 + 2 * q);

    #pragma unroll
    for (int i = 0; i < PATCH; ++i) {
        const float p = patch[i];
        const f2 pp = { p, p };
        const f4* row = (const f4*)(wsw + i * 28);
        #pragma unroll
        for (int j = 0; j < 7; ++j) {
            const f4 wq = row[j];
            const f2 lo = { wq.x, wq.y };
            const f2 hi = { wq.z, wq.w };
            ow[2 * j]     = __builtin_elementwise_fma(lo, pp, ow[2 * j]);
            ow[2 * j + 1] = __builtin_elementwise_fma(hi, pp, ow[2 * j + 1]);
        }
    }

    f2 acc01 = { b_def[0], b_def[1] };
    float acc2 = b_def[2];

    // ---- 9 taps, fully unrolled, branch-free unified sampling ----
    #pragma unroll
    for (int k = 0; k < KK; ++k) {
        const float* blk = wsw + 756 + k * 16;

        const float oy = ow[k].x;
        const float ox = ow[k].y;
        const float om = (k < 8) ? ((k & 1) ? ow[9 + (k >> 1)].y
                                            : ow[9 + (k >> 1)].x)
                                 : ow[13].x;

        const float m = __builtin_amdgcn_rcpf(1.0f + __expf(-om));

        const float py = (float)h + (float)(k / 3 - 1) + oy;
        const float px = (float)w + (float)(k % 3 - 1) + ox;
        const float y0f = floorf(py);
        const float x0f = floorf(px);
        const float dy = py - y0f;
        const float dx = px - x0f;
        const int y0 = (int)y0f;
        const int x0 = (int)x0f;

        // x side: load pair at xL, remap weights onto loaded elements
        const int xL = min(max(x0, 0), WW - 2);
        const float w0p = 1.0f - dx;
        const float w1p = dx;
        const bool P = (x0 == xL);        // interior in x
        const bool Q = (x0 + 1 == xL);    // x0 == -1
        const bool R = (x0 - 1 == xL);    // x0 == WW-1
        const float wa = P ? w0p : (Q ? w1p : 0.0f);
        const float wb = P ? w1p : (R ? w0p : 0.0f);

        // y side: clamp rows, fold validity and mask m into row weights
        const int yc0 = min(max(y0, 0), HH - 1);
        const int yc1 = min(max(y0 + 1, 0), HH - 1);
        const float ady = ((unsigned)y0 < HH)       ? (1.0f - dy) * m : 0.0f;
        const float bdy = ((unsigned)(y0 + 1) < HH) ? dy * m          : 0.0f;

        const f2 wxp = { wa, wb };
        const f2 wTe = wxp * ady;
        const f2 wBe = wxp * bdy;

        const int off0 = yc0 * WW + xL;
        const int off1 = yc1 * WW + xL;

        #pragma unroll
        for (int c = 0; c < CIN; ++c) {
            const float* xp = xb + c * plane;
            const f2 vT = *(const f2u*)(xp + off0);
            const f2 vB = *(const f2u*)(xp + off1);
            f2 s = vT * wTe;
            s = __builtin_elementwise_fma(vB, wBe, s);
            const float val = s.x + s.y;
            const f4 wq = *(const f4*)(blk + 4 * c);   // (wd0, wd1, wd2, 0)
            const f2 w01 = { wq.x, wq.y };
            const f2 vv = { val, val };
            acc01 = __builtin_elementwise_fma(w01, vv, acc01);
            acc2 = fmaf(wq.z, val, acc2);
        }
    }

    const size_t base = (size_t)b * (CIN * plane) + (size_t)h * WW + w;
    out[base]             = acc01.x;
    out[base + plane]     = acc01.y;
    out[base + 2 * plane] = acc2;
}

extern "C" void kernel_launch(void* const* d_in, const int* in_sizes, int n_in,
                              void* d_out, int out_size, void* d_ws, size_t ws_size,
                              hipStream_t stream) {
    const float* x     = (const float*)d_in[0];
    const float* w_off = (const float*)d_in[1];
    const float* b_off = (const float*)d_in[2];
    const float* w_def = (const float*)d_in[3];
    const float* b_def = (const float*)d_in[4];
    float* out = (float*)d_out;
    float* wsw = (float*)d_ws;   // 928 floats of reordered weights

    reorder_weights<<<1, 256, 0, stream>>>(w_off, b_off, w_def, wsw);

    dim3 block(256, 1, 1);
    dim3 grid(WW / 256, HH, BN);  // (2, 512, 8)
    deform_fused_kernel<<<grid, block, 0, stream>>>(x, wsw, b_def, out);
}